// Round 2
// 2664.017 us; speedup vs baseline: 1.4844x; 1.4844x over previous
//
#include <hip/hip_runtime.h>
#include <math.h>

// B=128, H=512, T=1024, IN=8. Sequential RNN, S=1023 steps.
// Persistent kernel: 256 blocks x 512 threads (1 block/CU).
// 32 groups x 8 j-blocks; group g handles batches [g*4, g*4+4).
// Block jb holds W_rec rows [jb*64, jb*64+64) in VGPRs (16 float4/thread).
//
// h exchange v3: SELF-TAGGED fp32 values, poll-on-data, 512 KB workspace.
//   h = tanh(..) in [-1,1]. Producer at iter s stores f = h + (+3 / -3)
//   selected by phase = (s>>1)&1, as ONE relaxed agent-scope 4B atomic.
//   Readiness = range check (f>=1.5 or f<=-1.5); memset(0) never matches.
//   Tag travels with the value => no vmcnt drain, no counter, no separate
//   reload. Wave wv only needs the chunk produced by block jb'=wv, so each
//   wave polls its own 4 words/lane and proceeds independently; the
//   successful poll already holds the data.
//   Safety: ping-pong (s&1) + phase bit. Slot polled at iter s can only
//   contain producer iter s-1 or s-3 (per-location coherence: this lane
//   already read the s-3 value from this address at poll s-2), and those
//   differ in phase. Overwrite of slot s-1 data (at producer iter s+1)
//   requires all blocks past B3@s+1 => all polls@s done. Decode error
//   ((h+3)-3 vs h) <= 2.4e-7, noise vs harness tolerance.
// Barriers: raw s_barrier + lgkmcnt(0) (+sched_barrier fences) — no
//   __syncthreads vmcnt(0) store-ack drain on the critical path.

#define BB  128
#define HH  512
#define TT  1024
#define SS  1023
#define NIN 8
#define NG  32      // groups
#define BPG 4       // batches per group
#define NJB 8       // j-blocks per group
#define JBS 64      // h rows per j-block
#define NTH 512
#define HBH (NG * BPG * HH)   // fp32 elems per ping-pong half (65536)

#define BAR_LGKM() do {                                          \
    __builtin_amdgcn_sched_barrier(0);                           \
    __asm__ volatile("s_waitcnt lgkmcnt(0)" ::: "memory");       \
    __builtin_amdgcn_s_barrier();                                \
    __builtin_amdgcn_sched_barrier(0);                           \
} while (0)

__launch_bounds__(NTH, 2)
__global__ void rnn_persist(const float* __restrict__ inputs,   // [B][IN][T]
                            const float* __restrict__ W_in,     // [H][IN]
                            const float* __restrict__ b_in,     // [H]
                            const float* __restrict__ W_rec,    // [H][H]
                            const float* __restrict__ b_rec,    // [H]
                            const float* __restrict__ W_key,    // [2][H]
                            const float* __restrict__ b_key,    // [2]
                            float* __restrict__ out,
                            float* __restrict__ hbuf)           // [2][NG][BPG][HH] self-tagged
{
    const int tid  = threadIdx.x;
    const int lane = tid & 63;
    const int wv   = tid >> 6;            // 0..7
    const int g    = blockIdx.x & (NG - 1);
    const int jb   = blockIdx.x >> 5;     // 0..7
    const int b0   = g * BPG;
    const int j0   = jb * JBS;

    float* keys_out = out;                         // [B][2][T]
    float* prs_out  = out + (size_t)BB * 2 * TT;   // [B][4][T]
    float* hs_out   = out + (size_t)BB * 6 * TT;   // [B][H][T]

    __shared__ float lds_chunk[NJB][BPG][JBS];  // per-wave h_{s-1} chunk (8 KB)
    __shared__ float lds_part[8][BPG][JBS];     // [wave][b][j] partials (8 KB)
    __shared__ float lds_hs[BPG * JBS * 33];    // 32-step hs accum, stride 33
    __shared__ float lds_win[NIN][JBS];         // W_in slice (transposed)
    __shared__ float lds_wkey[2 * HH];
    __shared__ float lds_bias[JBS];             // b_in + b_rec
    __shared__ float lds_x2[2][BPG][NIN];       // x double buffer
    __shared__ float lds_key[BPG];              // key_{s-1}[b][0]
    __shared__ float lds_bkey[2];

    // ---- W_rec slice -> registers (16 float4 = 64 VGPRs)
    float4 w4[16];
    {
        const float4* wr = (const float4*)(W_rec + (size_t)(j0 + lane) * HH + wv * 64);
        #pragma unroll
        for (int i = 0; i < 16; ++i) w4[i] = wr[i];
    }
    // ---- static LDS init
    if (tid < NIN * JBS) {
        int i = tid >> 6, j = tid & 63;
        lds_win[i][j] = W_in[(size_t)(j0 + j) * NIN + i];
    }
    for (int i = tid; i < 2 * HH; i += NTH) lds_wkey[i] = W_key[i];
    if (tid < JBS) lds_bias[tid] = b_in[j0 + tid] + b_rec[j0 + tid];
    if (tid < BPG) lds_key[tid] = 1.0f;
    if (tid < 2)   lds_bkey[tid] = b_key[tid];
    for (int r = tid; r < BPG * JBS; r += NTH) lds_hs[r * 33] = 0.0f;  // zero col

    // ---- zero t=0 slots for keys/prs
    if (jb == 0) {
        if (tid < BPG * 2) keys_out[((size_t)(b0 + (tid >> 1)) * 2 + (tid & 1)) * TT] = 0.0f;
        if (tid < BPG * 4) prs_out [((size_t)(b0 + (tid >> 2)) * 4 + (tid & 3)) * TT] = 0.0f;
    }

    // wave wv's poll addresses: chunk from producer jb'=wv, 4 batches stride HH
    const float* psrc = hbuf + (size_t)g * (BPG * HH) + wv * JBS + lane;
    float*       pdst = hbuf + (size_t)g * (BPG * HH);

    __syncthreads();

    for (int s = 0; s < SS; ++s) {
        // -- stage x_s (independent of h; double-buffered on s&1)
        if (tid >= NTH - 32) {
            int t = tid - (NTH - 32), b = t >> 3, i = t & 7;
            lds_x2[s & 1][b][i] = inputs[(size_t)(b0 + b) * NIN * TT + (size_t)i * TT + (s + 1)];
        }
        // -- per-wave: poll own self-tagged chunk of h_{s-1}; poll IS the fetch
        if (s > 0) {
            const float* p = psrc + (size_t)((s - 1) & 1) * HBH;
            // producer iter s-1: phase = ((s-1)>>1)&1; 0 -> f>=1.5, 1 -> f<=-1.5
            const int neg = ((s - 1) >> 1) & 1;
            const float off = neg ? -3.0f : 3.0f;
            float v0, v1, v2, v3;
            int rdy;
            do {
                v0 = __hip_atomic_load(p,          __ATOMIC_RELAXED, __HIP_MEMORY_SCOPE_AGENT);
                v1 = __hip_atomic_load(p + HH,     __ATOMIC_RELAXED, __HIP_MEMORY_SCOPE_AGENT);
                v2 = __hip_atomic_load(p + 2 * HH, __ATOMIC_RELAXED, __HIP_MEMORY_SCOPE_AGENT);
                v3 = __hip_atomic_load(p + 3 * HH, __ATOMIC_RELAXED, __HIP_MEMORY_SCOPE_AGENT);
                if (neg)
                    rdy = (v0 <= -1.5f) & (v1 <= -1.5f) & (v2 <= -1.5f) & (v3 <= -1.5f);
                else
                    rdy = (v0 >=  1.5f) & (v1 >=  1.5f) & (v2 >=  1.5f) & (v3 >=  1.5f);
            } while (!__all(rdy));
            lds_chunk[wv][0][lane] = v0 - off;
            lds_chunk[wv][1][lane] = v1 - off;
            lds_chunk[wv][2][lane] = v2 - off;
            lds_chunk[wv][3][lane] = v3 - off;
        } else {
            lds_chunk[wv][0][lane] = 0.0f;
            lds_chunk[wv][1][lane] = 0.0f;
            lds_chunk[wv][2][lane] = 0.0f;
            lds_chunk[wv][3][lane] = 0.0f;
        }

        // -- partial dots: W from regs, h broadcast from own wave's chunk
        //    (intra-wave ds_write->ds_read ordering only; no barrier needed)
        {
            const float4* hp = (const float4*)&lds_chunk[wv][0][0];
            float a0 = 0.f, a1 = 0.f, a2 = 0.f, a3 = 0.f;
            #pragma unroll
            for (int kk = 0; kk < 16; ++kk) {
                float4 w  = w4[kk];
                float4 x0 = hp[kk], x1 = hp[16 + kk], x2 = hp[32 + kk], x3 = hp[48 + kk];
                a0 += w.x * x0.x + w.y * x0.y + w.z * x0.z + w.w * x0.w;
                a1 += w.x * x1.x + w.y * x1.y + w.z * x1.z + w.w * x1.w;
                a2 += w.x * x2.x + w.y * x2.y + w.z * x2.z + w.w * x2.w;
                a3 += w.x * x3.x + w.y * x3.y + w.z * x3.z + w.w * x3.w;
            }
            lds_part[wv][0][lane] = a0;
            lds_part[wv][1][lane] = a1;
            lds_part[wv][2][lane] = a2;
            lds_part[wv][3][lane] = a3;
        }
        BAR_LGKM();                                        // B3

        if (tid < BPG * JBS) {
            // -- finalize h_s for (b, j); self-tagged store (no drain, no flag)
            int b = tid >> 6, j = tid & 63;
            float pre = lds_bias[j];
            #pragma unroll
            for (int w = 0; w < 8; ++w) pre += lds_part[w][b][j];
            #pragma unroll
            for (int i = 0; i < NIN; ++i) pre += lds_x2[s & 1][b][i] * lds_win[i][j];
            float hv = tanhf(pre);
            float enc = hv + (((s >> 1) & 1) ? -3.0f : 3.0f);
            __hip_atomic_store(&pdst[(size_t)(s & 1) * HBH + (size_t)b * HH + j0 + j], enc,
                               __ATOMIC_RELAXED, __HIP_MEMORY_SCOPE_AGENT);
            lds_hs[(b * JBS + j) * 33 + ((s + 1) & 31)] = hv;
        } else if (jb == 0 && s > 0) {
            // -- key_{s-1} = sigmoid(h_{s-1} @ W_key^T + b_key); h from chunks
            int t2  = tid - 256;
            int dot = t2 >> 5;          // 0..7
            int b = dot >> 1, c = dot & 1, seg = t2 & 31;
            float p = 0.f;
            #pragma unroll
            for (int m = 0; m < 16; ++m) {
                int k = seg + 32 * m;
                p += lds_chunk[k >> 6][b][k & 63] * lds_wkey[c * HH + k];
            }
            #pragma unroll
            for (int off = 16; off > 0; off >>= 1) p += __shfl_down(p, off, 32);
            if (seg == 0) {
                float kv = 1.0f / (1.0f + __expf(-(p + lds_bkey[c])));
                keys_out[((size_t)(b0 + b) * 2 + c) * TT + s] = kv;
                if (c == 0) lds_key[b] = kv;
            }
        }
        BAR_LGKM();                                        // B4

        // -- prs (off critical path)
        if (jb == 0 && tid < BPG * 4) {
            int b = tid >> 2, c = tid & 3;
            float kv = lds_key[b];
            const float* xb = lds_x2[s & 1][b];
            float tmv, arm;
            if (c < 2) { tmv = xb[6]; arm = xb[c]; }
            else       { tmv = xb[7]; arm = xb[c] * kv + xb[c + 2] * (1.0f - kv); }
            float r = (tmv - arm) / (0.15f * arm);
            prs_out[((size_t)(b0 + b) * 4 + c) * TT + (s + 1)] = (tmv == 0.0f) ? 0.0f : r * r;
        }

        // -- flush 32 accumulated hs time-slots (128 B contiguous per row)
        if (((s + 1) & 31) == 31) {
            int u0 = s - 30;                  // multiple of 32
            int r = tid >> 1, half = tid & 1;
            int b = r >> 6, j = r & 63;
            float* dst = hs_out + ((size_t)(b0 + b) * HH + j0 + j) * TT + u0 + half * 16;
            const float* src = &lds_hs[r * 33 + half * 16];
            #pragma unroll
            for (int q = 0; q < 4; ++q) {
                float4 v = { src[4 * q], src[4 * q + 1], src[4 * q + 2], src[4 * q + 3] };
                *(float4*)(dst + 4 * q) = v;
            }
        }
    }

    // -- final key (slot T-1) from h_{S-1}: poll self-tagged buffer directly
    if (jb == 0 && tid >= 256) {
        int t2  = tid - 256;
        int dot = t2 >> 5;
        int b = dot >> 1, c = dot & 1, seg = t2 & 31;
        // producer iter SS-1 = 1022: phase = (1022>>1)&1 = 1 -> f <= -1.5
        const float* hb = hbuf + (size_t)((SS - 1) & 1) * HBH
                        + (size_t)g * (BPG * HH) + (size_t)b * HH;
        float p = 0.f;
        #pragma unroll
        for (int m = 0; m < 16; ++m) {
            int k = seg + 32 * m;
            float v;
            do {
                v = __hip_atomic_load(hb + k, __ATOMIC_RELAXED, __HIP_MEMORY_SCOPE_AGENT);
            } while (!(v <= -1.5f));
            p += (v + 3.0f) * lds_wkey[c * HH + k];
        }
        #pragma unroll
        for (int off = 16; off > 0; off >>= 1) p += __shfl_down(p, off, 32);
        if (seg == 0) {
            float kv = 1.0f / (1.0f + __expf(-(p + lds_bkey[c])));
            keys_out[((size_t)(b0 + b) * 2 + c) * TT + (TT - 1)] = kv;
        }
    }
}

extern "C" void kernel_launch(void* const* d_in, const int* in_sizes, int n_in,
                              void* d_out, int out_size, void* d_ws, size_t ws_size,
                              hipStream_t stream) {
    const float* inputs = (const float*)d_in[0];
    const float* W_in   = (const float*)d_in[1];
    const float* b_in   = (const float*)d_in[2];
    const float* W_rec  = (const float*)d_in[3];
    const float* b_rec  = (const float*)d_in[4];
    const float* W_key  = (const float*)d_in[5];
    const float* b_key  = (const float*)d_in[6];
    float* outp = (float*)d_out;

    // ws layout: self-tagged h ping-pong buffer [2][NG][BPG][HH] fp32 = 512 KB
    // (within the 640 KB proven available). memset(0) each launch: encoded
    // values are in [2,4] or [-4,-2], so zero never reads as ready.
    float* hbuf = (float*)d_ws;
    hipMemsetAsync(d_ws, 0, (size_t)2 * HBH * sizeof(float), stream);

    rnn_persist<<<dim3(NG * NJB), dim3(NTH), 0, stream>>>(
        inputs, W_in, b_in, W_rec, b_rec, W_key, b_key, outp, hbuf);
}

// Round 3
// 2570.534 us; speedup vs baseline: 1.5384x; 1.0364x over previous
//
#include <hip/hip_runtime.h>
#include <math.h>

// B=128, H=512, T=1024, IN=8. Sequential RNN, S=1023 steps.
// Persistent kernel: 256 blocks x 512 threads (1 block/CU).
// v4 geometry: 64 groups x 4 j-blocks; group g handles batches [g*2, g*2+2).
//   Block jb owns W_rec rows [jb*128, jb*128+128): lane holds TWO rows
//   (lane, lane+64) x k-slice [wv*64, wv*64+64) = 32 float4 = 128 VGPRs.
// h exchange: SELF-TAGGED fp32 (h +/-3 by phase (s>>1)&1), poll-on-data,
//   relaxed agent-scope 4B atomics, 512 KB ping-pong workspace (proven).
//   Wave wv polls exactly the k-slice it consumes (2 values/lane) --
//   the successful poll IS the data fetch.
// v4 dot: LDS-broadcast-free. Polled h stays in VGPRs; per k-index j the
//   value is broadcast via v_readlane -> SGPR and consumed by v_fmac with
//   an SGPR operand. 2 readlane + 4 FMA per j (384 VALU insts/wave/step),
//   zero LDS-pipe traffic in the dot (was 64 ds_read_b128/wave/step).
// Barriers: raw s_barrier + lgkmcnt(0) (+sched_barrier) -- no vmcnt drain.

#define BB  128
#define HH  512
#define TT  1024
#define SS  1023
#define NIN 8
#define NG  64      // groups
#define BPG 2       // batches per group
#define NJB 4       // j-blocks per group
#define JBS 128     // h rows per j-block
#define NTH 512
#define HBH (NG * BPG * HH)   // fp32 elems per ping-pong half (65536)

#define BAR_LGKM() do {                                          \
    __builtin_amdgcn_sched_barrier(0);                           \
    __asm__ volatile("s_waitcnt lgkmcnt(0)" ::: "memory");       \
    __builtin_amdgcn_s_barrier();                                \
    __builtin_amdgcn_sched_barrier(0);                           \
} while (0)

__device__ __forceinline__ float bcast(float v, int ln) {
    return __int_as_float(__builtin_amdgcn_readlane(__float_as_int(v), ln));
}

__launch_bounds__(NTH, 2)
__global__ void rnn_persist(const float* __restrict__ inputs,   // [B][IN][T]
                            const float* __restrict__ W_in,     // [H][IN]
                            const float* __restrict__ b_in,     // [H]
                            const float* __restrict__ W_rec,    // [H][H]
                            const float* __restrict__ b_rec,    // [H]
                            const float* __restrict__ W_key,    // [2][H]
                            const float* __restrict__ b_key,    // [2]
                            float* __restrict__ out,
                            float* __restrict__ hbuf)           // [2][NG][BPG][HH] self-tagged
{
    const int tid  = threadIdx.x;
    const int lane = tid & 63;
    const int wv   = tid >> 6;            // 0..7
    const int g    = blockIdx.x & (NG - 1);   // same-XCD group: bid%8 == g%8
    const int jb   = blockIdx.x >> 6;     // 0..3
    const int b0   = g * BPG;
    const int j0   = jb * JBS;

    float* keys_out = out;                         // [B][2][T]
    float* prs_out  = out + (size_t)BB * 2 * TT;   // [B][4][T]
    float* hs_out   = out + (size_t)BB * 6 * TT;   // [B][H][T]

    __shared__ float lds_chunk[8][BPG][64];     // h_{s-1} for key dot (jb==0)
    __shared__ float lds_part[8][BPG][JBS];     // [wave][b][j] partials (8 KB)
    __shared__ float lds_hs[BPG * JBS * 33];    // 32-step hs accum, stride 33
    __shared__ float lds_win[NIN][JBS];         // W_in slice (transposed)
    __shared__ float lds_wkey[2 * HH];
    __shared__ float lds_bias[JBS];             // b_in + b_rec
    __shared__ float lds_x2[2][BPG][NIN];       // x double buffer
    __shared__ float lds_key[BPG];              // key_{s-1}[b][0]
    __shared__ float lds_bkey[2];

    // ---- W_rec slice -> registers: 2 rows x 64 k = 32 float4 = 128 VGPRs
    float4 w0[16], w1[16];
    {
        const float4* wr0 = (const float4*)(W_rec + (size_t)(j0 + lane) * HH + wv * 64);
        const float4* wr1 = (const float4*)(W_rec + (size_t)(j0 + 64 + lane) * HH + wv * 64);
        #pragma unroll
        for (int i = 0; i < 16; ++i) { w0[i] = wr0[i]; w1[i] = wr1[i]; }
    }
    // ---- static LDS init
    for (int r = tid; r < NIN * JBS; r += NTH) {
        int i = r & 7, j = r >> 3;
        lds_win[i][j] = W_in[(size_t)(j0 + j) * NIN + i];
    }
    for (int i = tid; i < 2 * HH; i += NTH) lds_wkey[i] = W_key[i];
    if (tid < JBS) lds_bias[tid] = b_in[j0 + tid] + b_rec[j0 + tid];
    if (tid < BPG) lds_key[tid] = 1.0f;
    if (tid < 2)   lds_bkey[tid] = b_key[tid];
    for (int r = tid; r < BPG * JBS; r += NTH) lds_hs[r * 33] = 0.0f;  // zero col

    // ---- zero t=0 slots for keys/prs
    if (jb == 0) {
        if (tid < BPG * 2) keys_out[((size_t)(b0 + (tid >> 1)) * 2 + (tid & 1)) * TT] = 0.0f;
        if (tid < BPG * 4) prs_out [((size_t)(b0 + (tid >> 2)) * 4 + (tid & 3)) * TT] = 0.0f;
    }

    // wave wv polls k-slice [wv*64, wv*64+64): 2 values/lane (b=0,1)
    const float* psrc = hbuf + (size_t)g * (BPG * HH) + wv * 64 + lane;
    float*       pdst = hbuf + (size_t)g * (BPG * HH);

    __syncthreads();

    for (int s = 0; s < SS; ++s) {
        // -- stage x_s (independent of h; double-buffered on s&1)
        if (tid >= NTH - 16) {
            int t = tid - (NTH - 16), b = t >> 3, i = t & 7;
            lds_x2[s & 1][b][i] = inputs[(size_t)(b0 + b) * NIN * TT + (size_t)i * TT + (s + 1)];
        }
        // -- per-wave poll of self-tagged h_{s-1}; poll IS the fetch
        float h0, h1;
        if (s > 0) {
            const float* p = psrc + (size_t)((s - 1) & 1) * HBH;
            const int neg = ((s - 1) >> 1) & 1;     // producer iter s-1 phase
            const float off = neg ? -3.0f : 3.0f;
            float v0, v1;
            int rdy;
            do {
                v0 = __hip_atomic_load(p,      __ATOMIC_RELAXED, __HIP_MEMORY_SCOPE_AGENT);
                v1 = __hip_atomic_load(p + HH, __ATOMIC_RELAXED, __HIP_MEMORY_SCOPE_AGENT);
                rdy = neg ? ((v0 <= -1.5f) & (v1 <= -1.5f))
                          : ((v0 >=  1.5f) & (v1 >=  1.5f));
            } while (!__all(rdy));
            h0 = v0 - off;
            h1 = v1 - off;
        } else {
            h0 = 0.0f;
            h1 = 0.0f;
        }
        if (jb == 0) {                      // stage for key dot only
            lds_chunk[wv][0][lane] = h0;
            lds_chunk[wv][1][lane] = h1;
        }

        // -- dot: register-broadcast h via readlane, pure VALU (no LDS)
        {
            float a00 = 0.f, a01 = 0.f, a10 = 0.f, a11 = 0.f;
            #pragma unroll
            for (int q = 0; q < 16; ++q) {
                const float* wa = (const float*)&w0[q];
                const float* wb = (const float*)&w1[q];
                #pragma unroll
                for (int c = 0; c < 4; ++c) {
                    const int ln = q * 4 + c;
                    float s0 = bcast(h0, ln);       // h[k=wv*64+ln][b=0]
                    float s1 = bcast(h1, ln);       // h[k=wv*64+ln][b=1]
                    float wva = wa[c];              // W_rec[row=lane   ][k]
                    float wvb = wb[c];              // W_rec[row=lane+64][k]
                    a00 += wva * s0; a01 += wva * s1;
                    a10 += wvb * s0; a11 += wvb * s1;
                }
            }
            lds_part[wv][0][lane]      = a00;
            lds_part[wv][1][lane]      = a01;
            lds_part[wv][0][lane + 64] = a10;
            lds_part[wv][1][lane + 64] = a11;
        }
        BAR_LGKM();                                        // B3

        if (tid < BPG * JBS) {
            // -- finalize h_s for (b, j); self-tagged store (no drain, no flag)
            int b = tid >> 7, j = tid & 127;
            float pre = lds_bias[j];
            #pragma unroll
            for (int w = 0; w < 8; ++w) pre += lds_part[w][b][j];
            #pragma unroll
            for (int i = 0; i < NIN; ++i) pre += lds_x2[s & 1][b][i] * lds_win[i][j];
            float hv = tanhf(pre);
            float enc = hv + (((s >> 1) & 1) ? -3.0f : 3.0f);
            __hip_atomic_store(&pdst[(size_t)(s & 1) * HBH + (size_t)b * HH + j0 + j], enc,
                               __ATOMIC_RELAXED, __HIP_MEMORY_SCOPE_AGENT);
            lds_hs[(b * JBS + j) * 33 + ((s + 1) & 31)] = hv;
        } else if (jb == 0 && s > 0 && tid < 384) {
            // -- key_{s-1} = sigmoid(h_{s-1} @ W_key^T + b_key); h from chunks
            int t2  = tid - 256;
            int dot = t2 >> 5;          // 0..3
            int b = dot >> 1, c = dot & 1, seg = t2 & 31;
            float p = 0.f;
            #pragma unroll
            for (int m = 0; m < 16; ++m) {
                int k = seg + 32 * m;
                p += lds_chunk[k >> 6][b][k & 63] * lds_wkey[c * HH + k];
            }
            #pragma unroll
            for (int off = 16; off > 0; off >>= 1) p += __shfl_down(p, off, 32);
            if (seg == 0) {
                float kv = 1.0f / (1.0f + __expf(-(p + lds_bkey[c])));
                keys_out[((size_t)(b0 + b) * 2 + c) * TT + s] = kv;
                if (c == 0) lds_key[b] = kv;
            }
        }
        BAR_LGKM();                                        // B4

        // -- prs (off critical path)
        if (jb == 0 && tid < BPG * 4) {
            int b = tid >> 2, c = tid & 3;
            float kv = lds_key[b];
            const float* xb = lds_x2[s & 1][b];
            float tmv, arm;
            if (c < 2) { tmv = xb[6]; arm = xb[c]; }
            else       { tmv = xb[7]; arm = xb[c] * kv + xb[c + 2] * (1.0f - kv); }
            float r = (tmv - arm) / (0.15f * arm);
            prs_out[((size_t)(b0 + b) * 4 + c) * TT + (s + 1)] = (tmv == 0.0f) ? 0.0f : r * r;
        }

        // -- flush 32 accumulated hs time-slots (128 B contiguous per row)
        if (((s + 1) & 31) == 31) {
            int u0 = s - 30;                  // multiple of 32
            int r = tid >> 1, half = tid & 1;
            int b = r >> 7, j = r & 127;
            float* dst = hs_out + ((size_t)(b0 + b) * HH + j0 + j) * TT + u0 + half * 16;
            const float* src = &lds_hs[r * 33 + half * 16];
            #pragma unroll
            for (int q = 0; q < 4; ++q) {
                float4 v = { src[4 * q], src[4 * q + 1], src[4 * q + 2], src[4 * q + 3] };
                *(float4*)(dst + 4 * q) = v;
            }
        }
    }

    // -- final key (slot T-1) from h_{S-1}: poll self-tagged buffer directly
    if (jb == 0 && tid >= 256 && tid < 384) {
        int t2  = tid - 256;
        int dot = t2 >> 5;          // 0..3
        int b = dot >> 1, c = dot & 1, seg = t2 & 31;
        // producer iter SS-1 = 1022: phase = (1022>>1)&1 = 1 -> f <= -1.5
        const float* hb = hbuf + (size_t)((SS - 1) & 1) * HBH
                        + (size_t)g * (BPG * HH) + (size_t)b * HH;
        float p = 0.f;
        #pragma unroll
        for (int m = 0; m < 16; ++m) {
            int k = seg + 32 * m;
            float v;
            do {
                v = __hip_atomic_load(hb + k, __ATOMIC_RELAXED, __HIP_MEMORY_SCOPE_AGENT);
            } while (!(v <= -1.5f));
            p += (v + 3.0f) * lds_wkey[c * HH + k];
        }
        #pragma unroll
        for (int off = 16; off > 0; off >>= 1) p += __shfl_down(p, off, 32);
        if (seg == 0) {
            float kv = 1.0f / (1.0f + __expf(-(p + lds_bkey[c])));
            keys_out[((size_t)(b0 + b) * 2 + c) * TT + (TT - 1)] = kv;
        }
    }
}

extern "C" void kernel_launch(void* const* d_in, const int* in_sizes, int n_in,
                              void* d_out, int out_size, void* d_ws, size_t ws_size,
                              hipStream_t stream) {
    const float* inputs = (const float*)d_in[0];
    const float* W_in   = (const float*)d_in[1];
    const float* b_in   = (const float*)d_in[2];
    const float* W_rec  = (const float*)d_in[3];
    const float* b_rec  = (const float*)d_in[4];
    const float* W_key  = (const float*)d_in[5];
    const float* b_key  = (const float*)d_in[6];
    float* outp = (float*)d_out;

    // ws layout: self-tagged h ping-pong buffer [2][NG][BPG][HH] fp32 = 512 KB.
    // memset(0) each launch: encoded values live in [2,4] or [-4,-2], so a
    // zero word never reads as ready.
    float* hbuf = (float*)d_ws;
    hipMemsetAsync(d_ws, 0, (size_t)2 * HBH * sizeof(float), stream);

    rnn_persist<<<dim3(NG * NJB), dim3(NTH), 0, stream>>>(
        inputs, W_in, b_in, W_rec, b_rec, W_key, b_key, outp, hbuf);
}